// Round 13
// baseline (719.013 us; speedup 1.0000x reference)
//
#include <hip/hip_runtime.h>
#include <stdint.h>

#define NR 100000L   // N rows (multiple of 8 — keeps all b128 edges aligned)
#define KC 92        // split-K chunks for utx (92*1088 >= 100000)
#define CHN 1088L    // n-chunk per utx block = 17*64

typedef __attribute__((ext_vector_type(8))) short s16x8;
typedef __attribute__((ext_vector_type(4))) short s16x4;
typedef __attribute__((ext_vector_type(4))) float f32x4;

__device__ __forceinline__ unsigned short f2bf(float f) {
  union { float f; unsigned u; } v; v.f = f;
  unsigned r = v.u + 0x7FFFu + ((v.u >> 16) & 1u);   // RNE
  return (unsigned short)(r >> 16);
}
__device__ __forceinline__ float bf2f(unsigned short s) {
  union { unsigned u; float f; } v; v.u = ((unsigned)s) << 16;
  return v.f;
}
__device__ __forceinline__ f32x4 MF(s16x8 a, s16x8 b, f32x4 c) {
  return __builtin_amdgcn_mfma_f32_16x16x32_bf16(a, b, c, 0, 0, 0);
}

// ================= swizzled LDS tile [ROWS][64] bf16, unpadded =================
__device__ __forceinline__ int swz(int row, int col) {
  return row * 64 + (((col >> 3) ^ (row & 7)) << 3) + (col & 7);
}

__device__ __forceinline__ void gld16(const void* g, void* l) {
  __builtin_amdgcn_global_load_lds(
      (const __attribute__((address_space(1))) void*)g,
      (__attribute__((address_space(3))) void*)l, 16, 0, 0);
}

template<int ROWS>
__device__ __forceinline__ void stage_async(unsigned short* lds, const unsigned short* src,
    long pitch, long r0, long k0, int tid) {
  const int lane = tid & 63, w = tid >> 6;
  const int lr = lane >> 3, lc = lane & 7;
#pragma unroll
  for (int it = 0; it < ROWS / 32; ++it) {
    const int rowbase = w * (ROWS / 4) + it * 8;     // wave-uniform
    const int row = rowbase + lr;
    const int sc = lc ^ (row & 7);                   // inverse-swizzled source unit
    gld16(src + (r0 + row) * pitch + k0 + sc * 8, lds + rowbase * 64);
  }
}

template<int ROWS>
__device__ __forceinline__ void stage_guard(unsigned short* lds, const unsigned short* src,
    long pitch, long r0, long rlim, long k0, long klim, int tid) {
  const int f8 = tid & 7;
#pragma unroll
  for (int it = 0; it < ROWS / 32; ++it) {
    const int row = (tid >> 3) + it * 32;
    const long gr = r0 + row, gk = k0 + f8 * 8;
    s16x8 v = {};
    if (gr < rlim && gk < klim) v = *(const s16x8*)(src + gr * pitch + gk);
    *(s16x8*)(lds + row * 64 + ((f8 ^ (row & 7)) << 3)) = v;
  }
}

template<int ROWS>
__device__ __forceinline__ void stage_guard_f32(unsigned short* lds, const float* src,
    long pitch, long r0, long rlim, long k0, long klim, int tid) {
  const int f4 = tid & 15;
#pragma unroll
  for (int it = 0; it < ROWS / 16; ++it) {
    const int row = (tid >> 4) + it * 16;
    const long gr = r0 + row, gk = k0 + f4 * 4;
    f32x4 v = {};
    if (gr < rlim && gk < klim) v = *(const f32x4*)(src + gr * pitch + gk);
    s16x4 o;
    o[0] = (short)f2bf(v[0]); o[1] = (short)f2bf(v[1]);
    o[2] = (short)f2bf(v[2]); o[3] = (short)f2bf(v[3]);
    const int c = f4 >> 1, h = f4 & 1;
    *(s16x4*)(lds + row * 64 + ((c ^ (row & 7)) << 3) + h * 4) = o;
  }
}

// legacy scalar transposed stager (small-ws tier only)
__device__ __forceinline__ void stage_utr_f32(unsigned short* lds, const float* u,
    long n0, long m0, int tid) {
  const int mm = tid & 63;
  const int base = tid >> 6;
#pragma unroll
  for (int it = 0; it < 16; ++it) {
    const int nl = base + it * 4;
    const long n = n0 + nl;
    unsigned short v = 0;
    if (n < NR) v = f2bf(u[n * 512 + m0 + mm]);
    lds[swz(mm, nl)] = v;
  }
}

__device__ __forceinline__ s16x8 fragA(const unsigned short* lds, int row, int kk, int lane) {
  const int c = kk * 4 + (lane >> 4);
  return *(const s16x8*)(lds + row * 64 + ((c ^ (row & 7)) << 3));
}

// ---------- prep ----------
__global__ void k_prep(const float* __restrict__ e0, const float* __restrict__ e1,
    const float* __restrict__ fe_w1, const float* __restrict__ fe_w2,
    const float* __restrict__ eig_w, const float* __restrict__ eig_b,
    const float* __restrict__ lw, const float* __restrict__ fW,
    unsigned short* __restrict__ W1T, unsigned short* __restrict__ W2T,
    float* __restrict__ eig, float* __restrict__ coef) {
  long id = (long)blockIdx.x * 256 + threadIdx.x;
  if (id < 65536) {                       // W1T[j][k]
    int j = (int)(id >> 9), k = (int)(id & 511);
    W1T[id] = (k < 500) ? f2bf(fe_w1[(long)k * 128 + j]) : (unsigned short)0;
  } else if (id < 65536 + 16384) {        // W2T[j][k]
    long q = id - 65536; int j = (int)(q >> 7), k = (int)(q & 127);
    W2T[q] = f2bf(fe_w2[(long)k * 128 + j]);
  } else if (id < 65536 + 16384 + 1024) { // eig[b][m]
    long q = id - 65536 - 16384; int b = (int)(q >> 9), m = (int)(q & 511);
    const float* e = b ? e1 : e0;
    float s = eig_b[0] + eig_w[0];
    float pe = 3.14159265358979323846f * e[m];
    for (int f = 1; f <= 128; ++f) s += cosf(pe * (float)f) * eig_w[f];
    eig[q] = s;
  } else if (id < 65536 + 16384 + 1024 + 256) { // coef[L][{c0,c1}][j]
    long q = id - 65536 - 16384 - 1024; int L = (int)(q >> 7), j = (int)(q & 127);
    float tail = 0.f;
    for (int k = 1; k <= 10; ++k) tail += fW[k];
    float w0 = lw[L * 256 + j], w1 = lw[L * 256 + 128 + j];
    coef[L * 256 + j] = w0 + fW[0] * w1;
    coef[L * 256 + 128 + j] = tail * w1;
  }
}

// ---------- convert+transpose u: Ubf[n][m] and UbT[m][n] ----------
__global__ __launch_bounds__(256) void k_cvtT(const float* __restrict__ u,
    unsigned short* __restrict__ Ubf, unsigned short* __restrict__ UbT) {
  __shared__ float T[64 * 64];
  const int tid = threadIdx.x;
  const int nt = blockIdx.x >> 3, mt = blockIdx.x & 7;
  const long n0 = (long)nt * 64, m0 = (long)mt * 64;
  const int r = tid >> 3;           // 0..31
  const int c8 = (tid & 7) * 8;
  const int u0 = c8 >> 2;           // base 16B unit (even)
#pragma unroll
  for (int p = 0; p < 2; ++p) {
    const int rr = r + p * 32;
    const long n = n0 + rr;
    f32x4 a = {}, b = {};
    if (n < NR) {
      a = *(const f32x4*)(u + n * 512 + m0 + c8);
      b = *(const f32x4*)(u + n * 512 + m0 + c8 + 4);
    }
    const int sw = (rr >> 3) & 7;
    *(f32x4*)&T[rr * 64 + ((u0 ^ sw) << 2)] = a;
    *(f32x4*)&T[rr * 64 + (((u0 + 1) ^ sw) << 2)] = b;
    if (n < NR) {
      s16x8 o;
      o[0] = (short)f2bf(a[0]); o[1] = (short)f2bf(a[1]);
      o[2] = (short)f2bf(a[2]); o[3] = (short)f2bf(a[3]);
      o[4] = (short)f2bf(b[0]); o[5] = (short)f2bf(b[1]);
      o[6] = (short)f2bf(b[2]); o[7] = (short)f2bf(b[3]);
      *(s16x8*)(Ubf + n * 512 + m0 + c8) = o;
    }
  }
  __syncthreads();
  const int nb8 = (tid & 7) * 8;
  const int sw2 = tid & 7;
#pragma unroll
  for (int p = 0; p < 2; ++p) {
    const int mm = r + p * 32;
    const int mu = mm >> 2, ml = mm & 3;
    s16x8 o;
#pragma unroll
    for (int e = 0; e < 8; ++e)
      o[e] = (short)f2bf(T[(nb8 + e) * 64 + (((mu) ^ sw2) << 2) + ml]);
    const long nb = n0 + nb8;
    if (nb + 7 < NR) {
      *(s16x8*)(UbT + (long)(m0 + mm) * NR + nb) = o;
    } else {
#pragma unroll
      for (int e = 0; e < 8; ++e)
        if (nb + e < NR) UbT[(long)(m0 + mm) * NR + nb + e] = o[e];
    }
  }
}

// ---------- GEMM1 (128x128 row-wave, f32-A staging): t = relu(x @ W1 + b1) ----------
__global__ __launch_bounds__(256) void k_gemm1(const float* __restrict__ x,
    const unsigned short* __restrict__ W1T, const float* __restrict__ b1,
    unsigned short* __restrict__ t) {
  __shared__ __align__(16) unsigned short Al[128 * 64];
  __shared__ __align__(16) unsigned short Bl[128 * 64];
  const int tid = threadIdx.x, lane = tid & 63, w = tid >> 6;
  const long n0 = (long)blockIdx.x * 128;
  f32x4 acc[2][8] = {};
  for (int kt = 0; kt < 8; ++kt) {
    stage_guard_f32<128>(Al, x, 500, n0, NR, kt * 64L, 500, tid);
    stage_async<128>(Bl, W1T, 512, 0, kt * 64L, tid);
    __syncthreads();
#pragma unroll
    for (int kk = 0; kk < 2; ++kk) {
      s16x8 af0 = fragA(Al, w * 32 + (lane & 15), kk, lane);
      s16x8 af1 = fragA(Al, w * 32 + 16 + (lane & 15), kk, lane);
#pragma unroll
      for (int ct = 0; ct < 8; ++ct) {
        s16x8 bfr = fragA(Bl, ct * 16 + (lane & 15), kk, lane);
        acc[0][ct] = MF(af0, bfr, acc[0][ct]);
        acc[1][ct] = MF(af1, bfr, acc[1][ct]);
      }
    }
    __syncthreads();
  }
  const int cl = lane & 15, g = lane >> 4;
#pragma unroll
  for (int ct = 0; ct < 8; ++ct) {
    const int j = ct * 16 + cl;
    const float bias = b1[j];
#pragma unroll
    for (int rt = 0; rt < 2; ++rt)
#pragma unroll
      for (int r = 0; r < 4; ++r) {
        const long n = n0 + w * 32 + rt * 16 + (g << 2) + r;
        if (n < NR) {
          float v = acc[rt][ct][r] + bias;
          t[n * 128 + j] = f2bf(v > 0.f ? v : 0.f);
        }
      }
  }
}

// ---------- GEMM2 (128x128 col-wave, async): hT = (t @ W2 + b2)^T ----------
__global__ __launch_bounds__(256) void k_gemm2(const unsigned short* __restrict__ W2T,
    const unsigned short* __restrict__ t, const float* __restrict__ b2,
    unsigned short* __restrict__ hT) {
  __shared__ __align__(16) unsigned short Al[128 * 64];
  __shared__ __align__(16) unsigned short Bl[128 * 64];
  const int tid = threadIdx.x, lane = tid & 63, w = tid >> 6;
  const long n0 = (long)blockIdx.x * 128;
  const bool edge = (n0 + 128) > NR;
  f32x4 acc[8][2] = {};
  for (int kt = 0; kt < 2; ++kt) {
    stage_async<128>(Al, W2T, 128, 0, kt * 64L, tid);
    if (!edge) stage_async<128>(Bl, t, 128, n0, kt * 64L, tid);
    else       stage_guard<128>(Bl, t, 128, n0, NR, kt * 64L, 128, tid);
    __syncthreads();
#pragma unroll
    for (int kk = 0; kk < 2; ++kk) {
      s16x8 bf0 = fragA(Bl, w * 32 + (lane & 15), kk, lane);
      s16x8 bf1 = fragA(Bl, w * 32 + 16 + (lane & 15), kk, lane);
#pragma unroll
      for (int rt = 0; rt < 8; ++rt) {
        s16x8 af = fragA(Al, rt * 16 + (lane & 15), kk, lane);
        acc[rt][0] = MF(af, bf0, acc[rt][0]);
        acc[rt][1] = MF(af, bf1, acc[rt][1]);
      }
    }
    __syncthreads();
  }
  const int cl = lane & 15, g = lane >> 4;
#pragma unroll
  for (int rt = 0; rt < 8; ++rt)
#pragma unroll
    for (int r = 0; r < 4; ++r) {
      const int j = rt * 16 + (g << 2) + r;
      const float bias = b2[j];
#pragma unroll
      for (int ct = 0; ct < 2; ++ct) {
        const long n = n0 + w * 32 + ct * 16 + cl;
        if (n < NR) hT[(long)j * NR + n] = f2bf(acc[rt][ct][r] + bias);
      }
    }
}

// ---------- utx (split-K, 128x128 col-wave, async, XCD-swizzled): bf16 P ----------
__global__ __launch_bounds__(256, 3) void k_utx(const unsigned short* __restrict__ hT,
    const unsigned short* __restrict__ UbT, unsigned short* __restrict__ P) {
  __shared__ __align__(16) unsigned short Al[128 * 64];
  __shared__ __align__(16) unsigned short Bl[128 * 64];
  const int tid = threadIdx.x, lane = tid & 63, w = tid >> 6;
  // XCD swizzle (grid 368 = 8 XCDs x 46): co-locate the 4 blocks sharing a
  // chunk's hT A-panel (278 KB, L2-sized) on the same XCD.
  const int bid = blockIdx.x;
  const int logical = (bid & 7) * 46 + (bid >> 3);
  const int mt = logical & 3, c = logical >> 2;
  const long m0 = (long)mt * 128, nb = (long)c * CHN;
  f32x4 acc[8][2] = {};
  for (int kt = 0; kt < 17; ++kt) {
    const long n0 = nb + kt * 64;
    if (n0 + 64 <= NR) {
      stage_async<128>(Al, hT, NR, 0, n0, tid);
      stage_async<128>(Bl, UbT, NR, m0, n0, tid);
    } else {
      stage_guard<128>(Al, hT, NR, 0, 1L << 40, n0, NR, tid);
      stage_guard<128>(Bl, UbT, NR, m0, 1L << 40, n0, NR, tid);
    }
    __syncthreads();
#pragma unroll
    for (int kk = 0; kk < 2; ++kk) {
      s16x8 bf0 = fragA(Bl, w * 32 + (lane & 15), kk, lane);
      s16x8 bf1 = fragA(Bl, w * 32 + 16 + (lane & 15), kk, lane);
#pragma unroll
      for (int rt = 0; rt < 8; ++rt) {
        s16x8 af = fragA(Al, rt * 16 + (lane & 15), kk, lane);
        acc[rt][0] = MF(af, bf0, acc[rt][0]);
        acc[rt][1] = MF(af, bf1, acc[rt][1]);
      }
    }
    __syncthreads();
  }
  const int cl = lane & 15, g = lane >> 4;
  unsigned short* Pc = P + (long)c * 65536;
#pragma unroll
  for (int rt = 0; rt < 8; ++rt)
#pragma unroll
    for (int r = 0; r < 4; ++r) {
      const int j = rt * 16 + (g << 2) + r;
#pragma unroll
      for (int ct = 0; ct < 2; ++ct) {
        const long m = m0 + w * 32 + ct * 16 + cl;
        Pc[(long)j * 512 + m] = f2bf(acc[rt][ct][r]);
      }
    }
}

// Legacy utx (64-tile, scalar transpose from f32 u), bf16 P
__global__ __launch_bounds__(256) void k_utx0(const unsigned short* __restrict__ hT,
    const float* __restrict__ u, unsigned short* __restrict__ P) {
  __shared__ __align__(16) unsigned short Al[128 * 64];
  __shared__ __align__(16) unsigned short Bl[64 * 64];
  const int tid = threadIdx.x, lane = tid & 63, w = tid >> 6;
  const int mt = blockIdx.x & 7, c = blockIdx.x >> 3;
  const long m0 = (long)mt * 64, nb = (long)c * CHN;
  f32x4 acc[8] = {};
  for (int kt = 0; kt < 17; ++kt) {
    const long n0 = nb + kt * 64;
    stage_guard<128>(Al, hT, NR, 0, 1L << 40, n0, NR, tid);
    stage_utr_f32(Bl, u, n0, m0, tid);
    __syncthreads();
#pragma unroll
    for (int kk = 0; kk < 2; ++kk) {
      s16x8 bfr = fragA(Bl, (w << 4) + (lane & 15), kk, lane);
#pragma unroll
      for (int rt = 0; rt < 8; ++rt) {
        s16x8 af = fragA(Al, (rt << 4) + (lane & 15), kk, lane);
        acc[rt] = MF(af, bfr, acc[rt]);
      }
    }
    __syncthreads();
  }
  const int cl = lane & 15, g = lane >> 4;
  const long m = m0 + (w << 4) + cl;
  unsigned short* Pc = P + (long)c * 65536;
#pragma unroll
  for (int rt = 0; rt < 8; ++rt)
#pragma unroll
    for (int r = 0; r < 4; ++r) {
      int j = (rt << 4) + (g << 2) + r;
      Pc[(long)j * 512 + m] = f2bf(acc[rt][r]);
    }
}

// ---------- reduce bf16 split-K partials, apply eig -> sT[j][m] bf16 ----------
__global__ void k_reduce(const unsigned short* __restrict__ P, const float* __restrict__ eig,
                         unsigned short* __restrict__ sT) {
  const int t4 = blockIdx.x * 256 + threadIdx.x;   // 16384 threads x 4 elems
  const int idx = t4 * 4;
  const int m = idx & 511;
  float s0 = 0.f, s1 = 0.f, s2 = 0.f, s3 = 0.f;
  const unsigned short* p = P + idx;
#pragma unroll 4
  for (int c = 0; c < KC; ++c) {
    s16x4 v = *(const s16x4*)(p + (long)c * 65536);
    s0 += bf2f((unsigned short)v[0]); s1 += bf2f((unsigned short)v[1]);
    s2 += bf2f((unsigned short)v[2]); s3 += bf2f((unsigned short)v[3]);
  }
  s16x4 o;
  o[0] = (short)f2bf(s0 * eig[m]);     o[1] = (short)f2bf(s1 * eig[m + 1]);
  o[2] = (short)f2bf(s2 * eig[m + 2]); o[3] = (short)f2bf(s3 * eig[m + 3]);
  *(s16x4*)(sT + idx) = o;
}

// ---------- r-GEMM (64-n col-wave, async, single-buffer) + LDS epilogue ----------
__global__ __launch_bounds__(256) void k_rgemm(const unsigned short* __restrict__ sT,
    const unsigned short* __restrict__ Ubf, const unsigned short* __restrict__ hin,
    unsigned short* __restrict__ hout, const float* __restrict__ c0,
    const float* __restrict__ c1, const float* __restrict__ gam,
    const float* __restrict__ bet) {
  __shared__ __align__(16) unsigned short Al[128 * 64];
  __shared__ __align__(16) unsigned short Bl[64 * 64];
  const int tid = threadIdx.x, lane = tid & 63, w = tid >> 6;
  const long n0 = (long)blockIdx.x * 64;
  const bool edge = (n0 + 64) > NR;
  f32x4 acc[8] = {};
  for (int kt = 0; kt < 8; ++kt) {
    stage_async<128>(Al, sT, 512, 0, kt * 64L, tid);
    if (!edge) stage_async<64>(Bl, Ubf, 512, n0, kt * 64L, tid);
    else       stage_guard<64>(Bl, Ubf, 512, n0, NR, kt * 64L, 512, tid);
    __syncthreads();
#pragma unroll
    for (int kk = 0; kk < 2; ++kk) {
      s16x8 bfr = fragA(Bl, (w << 4) + (lane & 15), kk, lane);
#pragma unroll
      for (int rt = 0; rt < 8; ++rt) {
        s16x8 af = fragA(Al, rt * 16 + (lane & 15), kk, lane);
        acc[rt] = MF(af, bfr, acc[rt]);
      }
    }
    __syncthreads();
  }
  // ---- stage hin tile [128 j][64 n] into Al ----
  if (!edge) stage_async<128>(Al, hin, NR, 0, n0, tid);
  else       stage_guard<128>(Al, hin, NR, 0, 1L << 40, n0, NR, tid);
  __syncthreads();
  const int cl = lane & 15, g = lane >> 4;
  const int nl = (w << 4) + cl;
  float sum = 0.f, ssq = 0.f;
#pragma unroll
  for (int rt = 0; rt < 8; ++rt)
#pragma unroll
    for (int r = 0; r < 4; ++r) {
      const int j = rt * 16 + (g << 2) + r;
      const float hp = bf2f(Al[swz(j, nl)]);
      const float pv = hp * c0[j] + c1[j] * acc[rt][r];
      acc[rt][r] = pv;
      sum += pv; ssq += pv * pv;
    }
  sum += __shfl_xor(sum, 16, 64); sum += __shfl_xor(sum, 32, 64);
  ssq += __shfl_xor(ssq, 16, 64); ssq += __shfl_xor(ssq, 32, 64);
  const float mu = sum * (1.f / 128.f);
  const float rs = rsqrtf(ssq * (1.f / 128.f) - mu * mu + 1e-5f);
  __syncthreads();
#pragma unroll
  for (int rt = 0; rt < 8; ++rt)
#pragma unroll
    for (int r = 0; r < 4; ++r) {
      const int j = rt * 16 + (g << 2) + r;
      float o = (acc[rt][r] - mu) * rs * gam[j] + bet[j];
      Al[swz(j, nl)] = f2bf(o > 0.f ? o : 0.f);
    }
  __syncthreads();
  const int f8 = tid & 7;
  const long gk = n0 + f8 * 8;
#pragma unroll
  for (int it = 0; it < 4; ++it) {
    const int j = (tid >> 3) + it * 32;
    const s16x8 v = *(const s16x8*)(Al + j * 64 + ((f8 ^ (j & 7)) << 3));
    if (gk + 7 < NR) {
      *(s16x8*)(hout + (long)j * NR + gk) = v;
    } else {
#pragma unroll
      for (int e = 0; e < 8; ++e)
        if (gk + e < NR) hout[(long)j * NR + gk + e] = v[e];
    }
  }
}

// Legacy r-GEMM (64-tile, f32 u)
__global__ __launch_bounds__(256) void k_rgemm64(const unsigned short* __restrict__ sT,
    const float* __restrict__ u, const unsigned short* __restrict__ hin,
    unsigned short* __restrict__ hout, const float* __restrict__ c0,
    const float* __restrict__ c1, const float* __restrict__ gam,
    const float* __restrict__ bet) {
  __shared__ __align__(16) unsigned short Al[128 * 64];
  __shared__ __align__(16) unsigned short Bl[64 * 64];
  const int tid = threadIdx.x, lane = tid & 63, w = tid >> 6;
  const long n0 = (long)blockIdx.x * 64;
  f32x4 acc[8] = {};
  for (int kt = 0; kt < 8; ++kt) {
    stage_guard<128>(Al, sT, 512, 0, 1L << 40, kt * 64L, 512, tid);
    stage_guard_f32<64>(Bl, u, 512, n0, NR, kt * 64L, 512, tid);
    __syncthreads();
#pragma unroll
    for (int kk = 0; kk < 2; ++kk) {
      s16x8 bfr = fragA(Bl, (w << 4) + (lane & 15), kk, lane);
#pragma unroll
      for (int rt = 0; rt < 8; ++rt) {
        s16x8 af = fragA(Al, (rt << 4) + (lane & 15), kk, lane);
        acc[rt] = MF(af, bfr, acc[rt]);
      }
    }
    __syncthreads();
  }
  const int cl = lane & 15, g = lane >> 4;
  const long n = n0 + (w << 4) + cl;
  const bool valid = n < NR;
  float sum = 0.f, ssq = 0.f;
#pragma unroll
  for (int rt = 0; rt < 8; ++rt)
#pragma unroll
    for (int r = 0; r < 4; ++r) {
      int j = (rt << 4) + (g << 2) + r;
      float hp = valid ? bf2f(hin[(long)j * NR + n]) : 0.f;
      float pv = hp * c0[j] + c1[j] * acc[rt][r];
      acc[rt][r] = pv;
      sum += pv; ssq += pv * pv;
    }
  sum += __shfl_xor(sum, 16, 64); sum += __shfl_xor(sum, 32, 64);
  ssq += __shfl_xor(ssq, 16, 64); ssq += __shfl_xor(ssq, 32, 64);
  const float mu = sum * (1.f / 128.f);
  const float rs = rsqrtf(ssq * (1.f / 128.f) - mu * mu + 1e-5f);
  if (valid) {
#pragma unroll
    for (int rt = 0; rt < 8; ++rt)
#pragma unroll
      for (int r = 0; r < 4; ++r) {
        int j = (rt << 4) + (g << 2) + r;
        float o = (acc[rt][r] - mu) * rs * gam[j] + bet[j];
        hout[(long)j * NR + n] = f2bf(o > 0.f ? o : 0.f);
      }
  }
}

// ---------- final: attention mix + 128->40 GEMV + log_softmax ----------
__global__ __launch_bounds__(256) void k_final(const unsigned short* __restrict__ R0,
    const unsigned short* __restrict__ R1, const unsigned short* __restrict__ R2,
    const float* __restrict__ att0, const float* __restrict__ att1,
    const float* __restrict__ att2, const float* __restrict__ av,
    const float* __restrict__ W, const float* __restrict__ bias,
    float* __restrict__ out) {
  __shared__ __align__(16) float Wl[128 * 40];
  __shared__ float Av[3][128];
  __shared__ float zb[256 * 41];
  const int tid = threadIdx.x;
  for (int i = tid; i < 5120; i += 256) Wl[i] = W[i];
  if (tid < 128) { Av[0][tid] = att0[tid]; Av[1][tid] = att1[tid]; Av[2][tid] = att2[tid]; }
  __syncthreads();
  const long n0 = (long)blockIdx.x * 256;
  const long n = n0 + tid;
  const long nn = n < NR ? n : NR - 1;
  float a0 = 0.f, a1 = 0.f, a2 = 0.f;
  for (int j = 0; j < 128; ++j) {
    a0 += bf2f(R0[(long)j * NR + nn]) * Av[0][j];
    a1 += bf2f(R1[(long)j * NR + nn]) * Av[1][j];
    a2 += bf2f(R2[(long)j * NR + nn]) * Av[2][j];
  }
  const float s0 = 1.f / (1.f + expf(-a0));
  const float s1 = 1.f / (1.f + expf(-a1));
  const float s2 = 1.f / (1.f + expf(-a2));
  const float l0 = s0 * av[0] + s1 * av[3] + s2 * av[6];
  const float l1 = s0 * av[1] + s1 * av[4] + s2 * av[7];
  const float l2 = s0 * av[2] + s1 * av[5] + s2 * av[8];
  const float mx = fmaxf(l0, fmaxf(l1, l2));
  const float e0v = expf(l0 - mx), e1v = expf(l1 - mx), e2v = expf(l2 - mx);
  const float inv = 1.f / (e0v + e1v + e2v);
  const float w0 = e0v * inv, w1 = e1v * inv, w2 = e2v * inv;
  float z[40];
#pragma unroll
  for (int c = 0; c < 40; ++c) z[c] = bias[c];
  for (int j = 0; j < 128; ++j) {
    const float h = w0 * bf2f(R0[(long)j * NR + nn]) + w1 * bf2f(R1[(long)j * NR + nn])
                  + w2 * bf2f(R2[(long)j * NR + nn]);
#pragma unroll
    for (int c4 = 0; c4 < 10; ++c4) {
      f32x4 wv = *(const f32x4*)(&Wl[j * 40 + c4 * 4]);
      z[c4 * 4 + 0] += h * wv[0];
      z[c4 * 4 + 1] += h * wv[1];
      z[c4 * 4 + 2] += h * wv[2];
      z[c4 * 4 + 3] += h * wv[3];
    }
  }
  float mz = z[0];
#pragma unroll
  for (int c = 1; c < 40; ++c) mz = fmaxf(mz, z[c]);
  float se = 0.f;
#pragma unroll
  for (int c = 0; c < 40; ++c) se += expf(z[c] - mz);
  const float ls = logf(se);
#pragma unroll
  for (int c = 0; c < 40; ++c) zb[tid * 41 + c] = z[c] - mz - ls;
  __syncthreads();
  long rows = NR - n0; if (rows > 256) rows = 256;
  const long cnt = rows * 40;
  for (long i = tid; i < cnt; i += 256)
    out[n0 * 40 + i] = zb[(i / 40) * 41 + (i % 40)];
}

extern "C" void kernel_launch(void* const* d_in, const int* in_sizes, int n_in,
                              void* d_out, int out_size, void* d_ws, size_t ws_size,
                              hipStream_t stream) {
  const float* x      = (const float*)d_in[0];
  const float* e0     = (const float*)d_in[1];
  const float* e1     = (const float*)d_in[2];
  const float* u0     = (const float*)d_in[3];
  const float* u1     = (const float*)d_in[4];
  const float* fe_w1  = (const float*)d_in[5];
  const float* fe_b1  = (const float*)d_in[6];
  const float* fe_w2  = (const float*)d_in[7];
  const float* fe_b2  = (const float*)d_in[8];
  const float* eig_w  = (const float*)d_in[9];
  const float* eig_bi = (const float*)d_in[10];
  const float* lw     = (const float*)d_in[11];
  const float* ln_g   = (const float*)d_in[12];
  const float* ln_b   = (const float*)d_in[13];
  const float* fW     = (const float*)d_in[14];
  const float* att0   = (const float*)d_in[15];
  const float* att1   = (const float*)d_in[16];
  const float* att2   = (const float*)d_in[17];
  const float* attv   = (const float*)d_in[18];
  const float* lin3w  = (const float*)d_in[19];
  const float* lin3b  = (const float*)d_in[20];
  float* out = (float*)d_out;

  const size_t SZ_H = (size_t)NR * 128 * 2;        // 25,600,000
  const size_t SZ_P = (size_t)KC * 65536 * 2;      // 12,058,624 (bf16 partials)
  const size_t SZ_U = (size_t)NR * 512 * 2;        // 102,400,000

  char* p = (char*)d_ws;
  unsigned short* R0T = (unsigned short*)p; p += SZ_H;
  unsigned short* R1T = (unsigned short*)p; p += SZ_H;
  unsigned short* R2T = (unsigned short*)p; p += SZ_H;
  unsigned short* P   = (unsigned short*)p; p += SZ_P;
  unsigned short* W1T = (unsigned short*)p; p += 131072;
  unsigned short* W2T = (unsigned short*)p; p += 32768;
  unsigned short* sT  = (unsigned short*)p; p += 131072;
  float* eig          = (float*)p;          p += 4096;
  float* coef         = (float*)p;          p += 2048;
  const size_t base = (size_t)(p - (char*)d_ws);
  const bool full = ws_size >= base + 2 * SZ_U;
  unsigned short* UbT = nullptr;
  unsigned short* Ubf = nullptr;
  if (full) {
    UbT = (unsigned short*)p; p += SZ_U;
    Ubf = (unsigned short*)p; p += SZ_U;
  }

  k_prep<<<325, 256, 0, stream>>>(e0, e1, fe_w1, fe_w2, eig_w, eig_bi, lw, fW,
                                  W1T, W2T, eig, coef);
  const int GB64  = (int)((NR + 63) / 64);     // 1563
  const int GB128 = (int)((NR + 127) / 128);   // 782

  k_gemm1<<<GB128, 256, 0, stream>>>(x, W1T, fe_b1, R1T);   // t -> R1T
  k_gemm2<<<GB128, 256, 0, stream>>>(W2T, R1T, fe_b2, R0T);

  for (int b = 0; b < 2; ++b) {
    const float* u = b ? u1 : u0;
    if (full) k_cvtT<<<GB64 * 8, 256, 0, stream>>>(u, Ubf, UbT);
    // h carries across branches: branch 1 starts from branch 0's final h (R1T).
    const unsigned short* hin = (b == 0) ? R0T : R1T;
    unsigned short* hb = b ? R2T : R1T;   // L0 out; L1 runs in-place on hb
    for (int L = 0; L < 2; ++L) {
      unsigned short* hout = hb;
      if (full) k_utx<<<4 * KC, 256, 0, stream>>>(hin, UbT, P);
      else      k_utx0<<<8 * KC, 256, 0, stream>>>(hin, u, P);
      k_reduce<<<64, 256, 0, stream>>>(P, eig + b * 512, sT);
      if (full)
        k_rgemm<<<GB64, 256, 0, stream>>>(sT, Ubf, hin, hout,
            coef + L * 256, coef + L * 256 + 128, ln_g + L * 128, ln_b + L * 128);
      else
        k_rgemm64<<<GB64, 256, 0, stream>>>(sT, u, hin, hout,
            coef + L * 256, coef + L * 256 + 128, ln_g + L * 128, ln_b + L * 128);
      hin = hout;
    }
  }
  k_final<<<(int)((NR + 255) / 256), 256, 0, stream>>>(R0T, R1T, R2T,
      att0, att1, att2, attv, lin3w, lin3b, out);
}

// Round 14
// 683.175 us; speedup vs baseline: 1.0525x; 1.0525x over previous
//
#include <hip/hip_runtime.h>
#include <stdint.h>

#define NR 100000L   // N rows (multiple of 8 — keeps all b128 edges aligned)
#define KC 92        // split-K chunks for utx (92*1088 >= 100000)
#define CHN 1088L    // n-chunk per utx block = 17*64

typedef __attribute__((ext_vector_type(8))) short s16x8;
typedef __attribute__((ext_vector_type(4))) short s16x4;
typedef __attribute__((ext_vector_type(4))) float f32x4;

__device__ __forceinline__ unsigned short f2bf(float f) {
  union { float f; unsigned u; } v; v.f = f;
  unsigned r = v.u + 0x7FFFu + ((v.u >> 16) & 1u);   // RNE
  return (unsigned short)(r >> 16);
}
__device__ __forceinline__ float bf2f(unsigned short s) {
  union { unsigned u; float f; } v; v.u = ((unsigned)s) << 16;
  return v.f;
}
__device__ __forceinline__ f32x4 MF(s16x8 a, s16x8 b, f32x4 c) {
  return __builtin_amdgcn_mfma_f32_16x16x32_bf16(a, b, c, 0, 0, 0);
}

// ================= swizzled LDS tile [ROWS][64] bf16, unpadded =================
__device__ __forceinline__ int swz(int row, int col) {
  return row * 64 + (((col >> 3) ^ (row & 7)) << 3) + (col & 7);
}

__device__ __forceinline__ void gld16(const void* g, void* l) {
  __builtin_amdgcn_global_load_lds(
      (const __attribute__((address_space(1))) void*)g,
      (__attribute__((address_space(3))) void*)l, 16, 0, 0);
}

template<int ROWS>
__device__ __forceinline__ void stage_async(unsigned short* lds, const unsigned short* src,
    long pitch, long r0, long k0, int tid) {
  const int lane = tid & 63, w = tid >> 6;
  const int lr = lane >> 3, lc = lane & 7;
#pragma unroll
  for (int it = 0; it < ROWS / 32; ++it) {
    const int rowbase = w * (ROWS / 4) + it * 8;     // wave-uniform
    const int row = rowbase + lr;
    const int sc = lc ^ (row & 7);                   // inverse-swizzled source unit
    gld16(src + (r0 + row) * pitch + k0 + sc * 8, lds + rowbase * 64);
  }
}

template<int ROWS>
__device__ __forceinline__ void stage_guard(unsigned short* lds, const unsigned short* src,
    long pitch, long r0, long rlim, long k0, long klim, int tid) {
  const int f8 = tid & 7;
#pragma unroll
  for (int it = 0; it < ROWS / 32; ++it) {
    const int row = (tid >> 3) + it * 32;
    const long gr = r0 + row, gk = k0 + f8 * 8;
    s16x8 v = {};
    if (gr < rlim && gk < klim) v = *(const s16x8*)(src + gr * pitch + gk);
    *(s16x8*)(lds + row * 64 + ((f8 ^ (row & 7)) << 3)) = v;
  }
}

template<int ROWS>
__device__ __forceinline__ void stage_guard_f32(unsigned short* lds, const float* src,
    long pitch, long r0, long rlim, long k0, long klim, int tid) {
  const int f4 = tid & 15;
#pragma unroll
  for (int it = 0; it < ROWS / 16; ++it) {
    const int row = (tid >> 4) + it * 16;
    const long gr = r0 + row, gk = k0 + f4 * 4;
    f32x4 v = {};
    if (gr < rlim && gk < klim) v = *(const f32x4*)(src + gr * pitch + gk);
    s16x4 o;
    o[0] = (short)f2bf(v[0]); o[1] = (short)f2bf(v[1]);
    o[2] = (short)f2bf(v[2]); o[3] = (short)f2bf(v[3]);
    const int c = f4 >> 1, h = f4 & 1;
    *(s16x4*)(lds + row * 64 + ((c ^ (row & 7)) << 3) + h * 4) = o;
  }
}

// legacy scalar transposed stager (small-ws tier only)
__device__ __forceinline__ void stage_utr_f32(unsigned short* lds, const float* u,
    long n0, long m0, int tid) {
  const int mm = tid & 63;
  const int base = tid >> 6;
#pragma unroll
  for (int it = 0; it < 16; ++it) {
    const int nl = base + it * 4;
    const long n = n0 + nl;
    unsigned short v = 0;
    if (n < NR) v = f2bf(u[n * 512 + m0 + mm]);
    lds[swz(mm, nl)] = v;
  }
}

__device__ __forceinline__ s16x8 fragA(const unsigned short* lds, int row, int kk, int lane) {
  const int c = kk * 4 + (lane >> 4);
  return *(const s16x8*)(lds + row * 64 + ((c ^ (row & 7)) << 3));
}

// ---------- prep ----------
__global__ void k_prep(const float* __restrict__ e0, const float* __restrict__ e1,
    const float* __restrict__ fe_w1, const float* __restrict__ fe_w2,
    const float* __restrict__ eig_w, const float* __restrict__ eig_b,
    const float* __restrict__ lw, const float* __restrict__ fW,
    unsigned short* __restrict__ W1T, unsigned short* __restrict__ W2T,
    float* __restrict__ eig, float* __restrict__ coef) {
  long id = (long)blockIdx.x * 256 + threadIdx.x;
  if (id < 65536) {                       // W1T[j][k]
    int j = (int)(id >> 9), k = (int)(id & 511);
    W1T[id] = (k < 500) ? f2bf(fe_w1[(long)k * 128 + j]) : (unsigned short)0;
  } else if (id < 65536 + 16384) {        // W2T[j][k]
    long q = id - 65536; int j = (int)(q >> 7), k = (int)(q & 127);
    W2T[q] = f2bf(fe_w2[(long)k * 128 + j]);
  } else if (id < 65536 + 16384 + 1024) { // eig[b][m]
    long q = id - 65536 - 16384; int b = (int)(q >> 9), m = (int)(q & 511);
    const float* e = b ? e1 : e0;
    float s = eig_b[0] + eig_w[0];
    float pe = 3.14159265358979323846f * e[m];
    for (int f = 1; f <= 128; ++f) s += cosf(pe * (float)f) * eig_w[f];
    eig[q] = s;
  } else if (id < 65536 + 16384 + 1024 + 256) { // coef[L][{c0,c1}][j]
    long q = id - 65536 - 16384 - 1024; int L = (int)(q >> 7), j = (int)(q & 127);
    float tail = 0.f;
    for (int k = 1; k <= 10; ++k) tail += fW[k];
    float w0 = lw[L * 256 + j], w1 = lw[L * 256 + 128 + j];
    coef[L * 256 + j] = w0 + fW[0] * w1;
    coef[L * 256 + 128 + j] = tail * w1;
  }
}

// ---------- convert+transpose u: Ubf[n][m] and UbT[m][n] ----------
__global__ __launch_bounds__(256) void k_cvtT(const float* __restrict__ u,
    unsigned short* __restrict__ Ubf, unsigned short* __restrict__ UbT) {
  __shared__ float T[64 * 64];
  const int tid = threadIdx.x;
  const int nt = blockIdx.x >> 3, mt = blockIdx.x & 7;
  const long n0 = (long)nt * 64, m0 = (long)mt * 64;
  const int r = tid >> 3;           // 0..31
  const int c8 = (tid & 7) * 8;
  const int u0 = c8 >> 2;           // base 16B unit (even)
#pragma unroll
  for (int p = 0; p < 2; ++p) {
    const int rr = r + p * 32;
    const long n = n0 + rr;
    f32x4 a = {}, b = {};
    if (n < NR) {
      a = *(const f32x4*)(u + n * 512 + m0 + c8);
      b = *(const f32x4*)(u + n * 512 + m0 + c8 + 4);
    }
    const int sw = (rr >> 3) & 7;
    *(f32x4*)&T[rr * 64 + ((u0 ^ sw) << 2)] = a;
    *(f32x4*)&T[rr * 64 + (((u0 + 1) ^ sw) << 2)] = b;
    if (n < NR) {
      s16x8 o;
      o[0] = (short)f2bf(a[0]); o[1] = (short)f2bf(a[1]);
      o[2] = (short)f2bf(a[2]); o[3] = (short)f2bf(a[3]);
      o[4] = (short)f2bf(b[0]); o[5] = (short)f2bf(b[1]);
      o[6] = (short)f2bf(b[2]); o[7] = (short)f2bf(b[3]);
      *(s16x8*)(Ubf + n * 512 + m0 + c8) = o;
    }
  }
  __syncthreads();
  const int nb8 = (tid & 7) * 8;
  const int sw2 = tid & 7;
#pragma unroll
  for (int p = 0; p < 2; ++p) {
    const int mm = r + p * 32;
    const int mu = mm >> 2, ml = mm & 3;
    s16x8 o;
#pragma unroll
    for (int e = 0; e < 8; ++e)
      o[e] = (short)f2bf(T[(nb8 + e) * 64 + (((mu) ^ sw2) << 2) + ml]);
    const long nb = n0 + nb8;
    if (nb + 7 < NR) {
      *(s16x8*)(UbT + (long)(m0 + mm) * NR + nb) = o;
    } else {
#pragma unroll
      for (int e = 0; e < 8; ++e)
        if (nb + e < NR) UbT[(long)(m0 + mm) * NR + nb + e] = o[e];
    }
  }
}

// ---------- GEMM1 (128x128 row-wave, f32-A reg-prefetch pipeline) ----------
// t = relu(x @ W1 + b1). Per kt: convert regs->LDS, issue W1T load_lds (oldest
// vmem -> barrier drains only these), THEN issue next x-tile loads into regs
// (stay in flight across the barrier, latency hidden under MFMA).
__global__ __launch_bounds__(256) void k_gemm1(const float* __restrict__ x,
    const unsigned short* __restrict__ W1T, const float* __restrict__ b1,
    unsigned short* __restrict__ t) {
  __shared__ __align__(16) unsigned short Al[128 * 64];
  __shared__ __align__(16) unsigned short Bl[128 * 64];
  const int tid = threadIdx.x, lane = tid & 63, w = tid >> 6;
  const long n0 = (long)blockIdx.x * 128;
  const int f4 = tid & 15;
  const int row_b = tid >> 4;          // rows row_b + it*16
  const int cu = f4 >> 1, hh = f4 & 1; // LDS swizzle sub-coords
  f32x4 xr[8];
  // prologue: load kt=0 x-tile (4|500 -> chunk guard exact)
#pragma unroll
  for (int it = 0; it < 8; ++it) {
    const int row = row_b + it * 16;
    const long gr = n0 + row, gk = f4 * 4;
    f32x4 v = {};
    if (gr < NR && gk < 500) v = *(const f32x4*)(x + gr * 500 + gk);
    xr[it] = v;
  }
  f32x4 acc[2][8] = {};
  for (int kt = 0; kt < 8; ++kt) {
    // 1) convert current regs -> LDS (swizzled)
#pragma unroll
    for (int it = 0; it < 8; ++it) {
      const int row = row_b + it * 16;
      s16x4 o;
      o[0] = (short)f2bf(xr[it][0]); o[1] = (short)f2bf(xr[it][1]);
      o[2] = (short)f2bf(xr[it][2]); o[3] = (short)f2bf(xr[it][3]);
      *(s16x4*)(Al + row * 64 + ((cu ^ (row & 7)) << 3) + hh * 4) = o;
    }
    // 2) B-operand async staging (issued before the prefetch)
    stage_async<128>(Bl, W1T, 512, 0, kt * 64L, tid);
    // 3) prefetch next x-tile into regs
    if (kt < 7) {
#pragma unroll
      for (int it = 0; it < 8; ++it) {
        const int row = row_b + it * 16;
        const long gr = n0 + row, gk = (kt + 1) * 64L + f4 * 4;
        f32x4 v = {};
        if (gr < NR && gk < 500) v = *(const f32x4*)(x + gr * 500 + gk);
        xr[it] = v;
      }
    }
    __syncthreads();
#pragma unroll
    for (int kk = 0; kk < 2; ++kk) {
      s16x8 af0 = fragA(Al, w * 32 + (lane & 15), kk, lane);
      s16x8 af1 = fragA(Al, w * 32 + 16 + (lane & 15), kk, lane);
#pragma unroll
      for (int ct = 0; ct < 8; ++ct) {
        s16x8 bfr = fragA(Bl, ct * 16 + (lane & 15), kk, lane);
        acc[0][ct] = MF(af0, bfr, acc[0][ct]);
        acc[1][ct] = MF(af1, bfr, acc[1][ct]);
      }
    }
    __syncthreads();
  }
  const int cl = lane & 15, g = lane >> 4;
#pragma unroll
  for (int ct = 0; ct < 8; ++ct) {
    const int j = ct * 16 + cl;
    const float bias = b1[j];
#pragma unroll
    for (int rt = 0; rt < 2; ++rt)
#pragma unroll
      for (int r = 0; r < 4; ++r) {
        const long n = n0 + w * 32 + rt * 16 + (g << 2) + r;
        if (n < NR) {
          float v = acc[rt][ct][r] + bias;
          t[n * 128 + j] = f2bf(v > 0.f ? v : 0.f);
        }
      }
  }
}

// ---------- GEMM2 (128x128 col-wave, async): hT = (t @ W2 + b2)^T ----------
__global__ __launch_bounds__(256) void k_gemm2(const unsigned short* __restrict__ W2T,
    const unsigned short* __restrict__ t, const float* __restrict__ b2,
    unsigned short* __restrict__ hT) {
  __shared__ __align__(16) unsigned short Al[128 * 64];
  __shared__ __align__(16) unsigned short Bl[128 * 64];
  const int tid = threadIdx.x, lane = tid & 63, w = tid >> 6;
  const long n0 = (long)blockIdx.x * 128;
  const bool edge = (n0 + 128) > NR;
  f32x4 acc[8][2] = {};
  for (int kt = 0; kt < 2; ++kt) {
    stage_async<128>(Al, W2T, 128, 0, kt * 64L, tid);
    if (!edge) stage_async<128>(Bl, t, 128, n0, kt * 64L, tid);
    else       stage_guard<128>(Bl, t, 128, n0, NR, kt * 64L, 128, tid);
    __syncthreads();
#pragma unroll
    for (int kk = 0; kk < 2; ++kk) {
      s16x8 bf0 = fragA(Bl, w * 32 + (lane & 15), kk, lane);
      s16x8 bf1 = fragA(Bl, w * 32 + 16 + (lane & 15), kk, lane);
#pragma unroll
      for (int rt = 0; rt < 8; ++rt) {
        s16x8 af = fragA(Al, rt * 16 + (lane & 15), kk, lane);
        acc[rt][0] = MF(af, bf0, acc[rt][0]);
        acc[rt][1] = MF(af, bf1, acc[rt][1]);
      }
    }
    __syncthreads();
  }
  const int cl = lane & 15, g = lane >> 4;
#pragma unroll
  for (int rt = 0; rt < 8; ++rt)
#pragma unroll
    for (int r = 0; r < 4; ++r) {
      const int j = rt * 16 + (g << 2) + r;
      const float bias = b2[j];
#pragma unroll
      for (int ct = 0; ct < 2; ++ct) {
        const long n = n0 + w * 32 + ct * 16 + cl;
        if (n < NR) hT[(long)j * NR + n] = f2bf(acc[rt][ct][r] + bias);
      }
    }
}

// ---------- utx (split-K, 128x128 col-wave, async, XCD-swizzled): bf16 P ----------
__global__ __launch_bounds__(256, 3) void k_utx(const unsigned short* __restrict__ hT,
    const unsigned short* __restrict__ UbT, unsigned short* __restrict__ P) {
  __shared__ __align__(16) unsigned short Al[128 * 64];
  __shared__ __align__(16) unsigned short Bl[128 * 64];
  const int tid = threadIdx.x, lane = tid & 63, w = tid >> 6;
  const int bid = blockIdx.x;
  const int logical = (bid & 7) * 46 + (bid >> 3);
  const int mt = logical & 3, c = logical >> 2;
  const long m0 = (long)mt * 128, nb = (long)c * CHN;
  f32x4 acc[8][2] = {};
  for (int kt = 0; kt < 17; ++kt) {
    const long n0 = nb + kt * 64;
    if (n0 + 64 <= NR) {
      stage_async<128>(Al, hT, NR, 0, n0, tid);
      stage_async<128>(Bl, UbT, NR, m0, n0, tid);
    } else {
      stage_guard<128>(Al, hT, NR, 0, 1L << 40, n0, NR, tid);
      stage_guard<128>(Bl, UbT, NR, m0, 1L << 40, n0, NR, tid);
    }
    __syncthreads();
#pragma unroll
    for (int kk = 0; kk < 2; ++kk) {
      s16x8 bf0 = fragA(Bl, w * 32 + (lane & 15), kk, lane);
      s16x8 bf1 = fragA(Bl, w * 32 + 16 + (lane & 15), kk, lane);
#pragma unroll
      for (int rt = 0; rt < 8; ++rt) {
        s16x8 af = fragA(Al, rt * 16 + (lane & 15), kk, lane);
        acc[rt][0] = MF(af, bf0, acc[rt][0]);
        acc[rt][1] = MF(af, bf1, acc[rt][1]);
      }
    }
    __syncthreads();
  }
  const int cl = lane & 15, g = lane >> 4;
  unsigned short* Pc = P + (long)c * 65536;
#pragma unroll
  for (int rt = 0; rt < 8; ++rt)
#pragma unroll
    for (int r = 0; r < 4; ++r) {
      const int j = rt * 16 + (g << 2) + r;
#pragma unroll
      for (int ct = 0; ct < 2; ++ct) {
        const long m = m0 + w * 32 + ct * 16 + cl;
        Pc[(long)j * 512 + m] = f2bf(acc[rt][ct][r]);
      }
    }
}

// Legacy utx (64-tile, scalar transpose from f32 u), bf16 P
__global__ __launch_bounds__(256) void k_utx0(const unsigned short* __restrict__ hT,
    const float* __restrict__ u, unsigned short* __restrict__ P) {
  __shared__ __align__(16) unsigned short Al[128 * 64];
  __shared__ __align__(16) unsigned short Bl[64 * 64];
  const int tid = threadIdx.x, lane = tid & 63, w = tid >> 6;
  const int mt = blockIdx.x & 7, c = blockIdx.x >> 3;
  const long m0 = (long)mt * 64, nb = (long)c * CHN;
  f32x4 acc[8] = {};
  for (int kt = 0; kt < 17; ++kt) {
    const long n0 = nb + kt * 64;
    stage_guard<128>(Al, hT, NR, 0, 1L << 40, n0, NR, tid);
    stage_utr_f32(Bl, u, n0, m0, tid);
    __syncthreads();
#pragma unroll
    for (int kk = 0; kk < 2; ++kk) {
      s16x8 bfr = fragA(Bl, (w << 4) + (lane & 15), kk, lane);
#pragma unroll
      for (int rt = 0; rt < 8; ++rt) {
        s16x8 af = fragA(Al, (rt << 4) + (lane & 15), kk, lane);
        acc[rt] = MF(af, bfr, acc[rt]);
      }
    }
    __syncthreads();
  }
  const int cl = lane & 15, g = lane >> 4;
  const long m = m0 + (w << 4) + cl;
  unsigned short* Pc = P + (long)c * 65536;
#pragma unroll
  for (int rt = 0; rt < 8; ++rt)
#pragma unroll
    for (int r = 0; r < 4; ++r) {
      int j = (rt << 4) + (g << 2) + r;
      Pc[(long)j * 512 + m] = f2bf(acc[rt][r]);
    }
}

// ---------- reduce bf16 split-K partials, apply eig -> sT[j][m] bf16 ----------
__global__ void k_reduce(const unsigned short* __restrict__ P, const float* __restrict__ eig,
                         unsigned short* __restrict__ sT) {
  const int t4 = blockIdx.x * 256 + threadIdx.x;   // 16384 threads x 4 elems
  const int idx = t4 * 4;
  const int m = idx & 511;
  float s0 = 0.f, s1 = 0.f, s2 = 0.f, s3 = 0.f;
  const unsigned short* p = P + idx;
#pragma unroll 4
  for (int c = 0; c < KC; ++c) {
    s16x4 v = *(const s16x4*)(p + (long)c * 65536);
    s0 += bf2f((unsigned short)v[0]); s1 += bf2f((unsigned short)v[1]);
    s2 += bf2f((unsigned short)v[2]); s3 += bf2f((unsigned short)v[3]);
  }
  s16x4 o;
  o[0] = (short)f2bf(s0 * eig[m]);     o[1] = (short)f2bf(s1 * eig[m + 1]);
  o[2] = (short)f2bf(s2 * eig[m + 2]); o[3] = (short)f2bf(s3 * eig[m + 3]);
  *(s16x4*)(sT + idx) = o;
}

// ---------- r-GEMM (64-n col-wave, async, single-buffer) + LDS epilogue ----------
__global__ __launch_bounds__(256) void k_rgemm(const unsigned short* __restrict__ sT,
    const unsigned short* __restrict__ Ubf, const unsigned short* __restrict__ hin,
    unsigned short* __restrict__ hout, const float* __restrict__ c0,
    const float* __restrict__ c1, const float* __restrict__ gam,
    const float* __restrict__ bet) {
  __shared__ __align__(16) unsigned short Al[128 * 64];
  __shared__ __align__(16) unsigned short Bl[64 * 64];
  const int tid = threadIdx.x, lane = tid & 63, w = tid >> 6;
  const long n0 = (long)blockIdx.x * 64;
  const bool edge = (n0 + 64) > NR;
  f32x4 acc[8] = {};
  for (int kt = 0; kt < 8; ++kt) {
    stage_async<128>(Al, sT, 512, 0, kt * 64L, tid);
    if (!edge) stage_async<64>(Bl, Ubf, 512, n0, kt * 64L, tid);
    else       stage_guard<64>(Bl, Ubf, 512, n0, NR, kt * 64L, 512, tid);
    __syncthreads();
#pragma unroll
    for (int kk = 0; kk < 2; ++kk) {
      s16x8 bfr = fragA(Bl, (w << 4) + (lane & 15), kk, lane);
#pragma unroll
      for (int rt = 0; rt < 8; ++rt) {
        s16x8 af = fragA(Al, rt * 16 + (lane & 15), kk, lane);
        acc[rt] = MF(af, bfr, acc[rt]);
      }
    }
    __syncthreads();
  }
  // ---- stage hin tile [128 j][64 n] into Al ----
  if (!edge) stage_async<128>(Al, hin, NR, 0, n0, tid);
  else       stage_guard<128>(Al, hin, NR, 0, 1L << 40, n0, NR, tid);
  __syncthreads();
  const int cl = lane & 15, g = lane >> 4;
  const int nl = (w << 4) + cl;
  float sum = 0.f, ssq = 0.f;
#pragma unroll
  for (int rt = 0; rt < 8; ++rt)
#pragma unroll
    for (int r = 0; r < 4; ++r) {
      const int j = rt * 16 + (g << 2) + r;
      const float hp = bf2f(Al[swz(j, nl)]);
      const float pv = hp * c0[j] + c1[j] * acc[rt][r];
      acc[rt][r] = pv;
      sum += pv; ssq += pv * pv;
    }
  sum += __shfl_xor(sum, 16, 64); sum += __shfl_xor(sum, 32, 64);
  ssq += __shfl_xor(ssq, 16, 64); ssq += __shfl_xor(ssq, 32, 64);
  const float mu = sum * (1.f / 128.f);
  const float rs = rsqrtf(ssq * (1.f / 128.f) - mu * mu + 1e-5f);
  __syncthreads();
#pragma unroll
  for (int rt = 0; rt < 8; ++rt)
#pragma unroll
    for (int r = 0; r < 4; ++r) {
      const int j = rt * 16 + (g << 2) + r;
      float o = (acc[rt][r] - mu) * rs * gam[j] + bet[j];
      Al[swz(j, nl)] = f2bf(o > 0.f ? o : 0.f);
    }
  __syncthreads();
  const int f8 = tid & 7;
  const long gk = n0 + f8 * 8;
#pragma unroll
  for (int it = 0; it < 4; ++it) {
    const int j = (tid >> 3) + it * 32;
    const s16x8 v = *(const s16x8*)(Al + j * 64 + ((f8 ^ (j & 7)) << 3));
    if (gk + 7 < NR) {
      *(s16x8*)(hout + (long)j * NR + gk) = v;
    } else {
#pragma unroll
      for (int e = 0; e < 8; ++e)
        if (gk + e < NR) hout[(long)j * NR + gk + e] = v[e];
    }
  }
}

// Legacy r-GEMM (64-tile, f32 u)
__global__ __launch_bounds__(256) void k_rgemm64(const unsigned short* __restrict__ sT,
    const float* __restrict__ u, const unsigned short* __restrict__ hin,
    unsigned short* __restrict__ hout, const float* __restrict__ c0,
    const float* __restrict__ c1, const float* __restrict__ gam,
    const float* __restrict__ bet) {
  __shared__ __align__(16) unsigned short Al[128 * 64];
  __shared__ __align__(16) unsigned short Bl[64 * 64];
  const int tid = threadIdx.x, lane = tid & 63, w = tid >> 6;
  const long n0 = (long)blockIdx.x * 64;
  f32x4 acc[8] = {};
  for (int kt = 0; kt < 8; ++kt) {
    stage_guard<128>(Al, sT, 512, 0, 1L << 40, kt * 64L, 512, tid);
    stage_guard_f32<64>(Bl, u, 512, n0, NR, kt * 64L, 512, tid);
    __syncthreads();
#pragma unroll
    for (int kk = 0; kk < 2; ++kk) {
      s16x8 bfr = fragA(Bl, (w << 4) + (lane & 15), kk, lane);
#pragma unroll
      for (int rt = 0; rt < 8; ++rt) {
        s16x8 af = fragA(Al, (rt << 4) + (lane & 15), kk, lane);
        acc[rt] = MF(af, bfr, acc[rt]);
      }
    }
    __syncthreads();
  }
  const int cl = lane & 15, g = lane >> 4;
  const long n = n0 + (w << 4) + cl;
  const bool valid = n < NR;
  float sum = 0.f, ssq = 0.f;
#pragma unroll
  for (int rt = 0; rt < 8; ++rt)
#pragma unroll
    for (int r = 0; r < 4; ++r) {
      int j = (rt << 4) + (g << 2) + r;
      float hp = valid ? bf2f(hin[(long)j * NR + n]) : 0.f;
      float pv = hp * c0[j] + c1[j] * acc[rt][r];
      acc[rt][r] = pv;
      sum += pv; ssq += pv * pv;
    }
  sum += __shfl_xor(sum, 16, 64); sum += __shfl_xor(sum, 32, 64);
  ssq += __shfl_xor(ssq, 16, 64); ssq += __shfl_xor(ssq, 32, 64);
  const float mu = sum * (1.f / 128.f);
  const float rs = rsqrtf(ssq * (1.f / 128.f) - mu * mu + 1e-5f);
  if (valid) {
#pragma unroll
    for (int rt = 0; rt < 8; ++rt)
#pragma unroll
      for (int r = 0; r < 4; ++r) {
        int j = (rt << 4) + (g << 2) + r;
        float o = (acc[rt][r] - mu) * rs * gam[j] + bet[j];
        hout[(long)j * NR + n] = f2bf(o > 0.f ? o : 0.f);
      }
  }
}

// ---------- final: attention mix + 128->40 GEMV + log_softmax ----------
__global__ __launch_bounds__(256) void k_final(const unsigned short* __restrict__ R0,
    const unsigned short* __restrict__ R1, const unsigned short* __restrict__ R2,
    const float* __restrict__ att0, const float* __restrict__ att1,
    const float* __restrict__ att2, const float* __restrict__ av,
    const float* __restrict__ W, const float* __restrict__ bias,
    float* __restrict__ out) {
  __shared__ __align__(16) float Wl[128 * 40];
  __shared__ float Av[3][128];
  __shared__ float zb[256 * 41];
  const int tid = threadIdx.x;
  for (int i = tid; i < 5120; i += 256) Wl[i] = W[i];
  if (tid < 128) { Av[0][tid] = att0[tid]; Av[1][tid] = att1[tid]; Av[2][tid] = att2[tid]; }
  __syncthreads();
  const long n0 = (long)blockIdx.x * 256;
  const long n = n0 + tid;
  const long nn = n < NR ? n : NR - 1;
  float a0 = 0.f, a1 = 0.f, a2 = 0.f;
  for (int j = 0; j < 128; ++j) {
    a0 += bf2f(R0[(long)j * NR + nn]) * Av[0][j];
    a1 += bf2f(R1[(long)j * NR + nn]) * Av[1][j];
    a2 += bf2f(R2[(long)j * NR + nn]) * Av[2][j];
  }
  const float s0 = 1.f / (1.f + expf(-a0));
  const float s1 = 1.f / (1.f + expf(-a1));
  const float s2 = 1.f / (1.f + expf(-a2));
  const float l0 = s0 * av[0] + s1 * av[3] + s2 * av[6];
  const float l1 = s0 * av[1] + s1 * av[4] + s2 * av[7];
  const float l2 = s0 * av[2] + s1 * av[5] + s2 * av[8];
  const float mx = fmaxf(l0, fmaxf(l1, l2));
  const float e0v = expf(l0 - mx), e1v = expf(l1 - mx), e2v = expf(l2 - mx);
  const float inv = 1.f / (e0v + e1v + e2v);
  const float w0 = e0v * inv, w1 = e1v * inv, w2 = e2v * inv;
  float z[40];
#pragma unroll
  for (int c = 0; c < 40; ++c) z[c] = bias[c];
  for (int j = 0; j < 128; ++j) {
    const float h = w0 * bf2f(R0[(long)j * NR + nn]) + w1 * bf2f(R1[(long)j * NR + nn])
                  + w2 * bf2f(R2[(long)j * NR + nn]);
#pragma unroll
    for (int c4 = 0; c4 < 10; ++c4) {
      f32x4 wv = *(const f32x4*)(&Wl[j * 40 + c4 * 4]);
      z[c4 * 4 + 0] += h * wv[0];
      z[c4 * 4 + 1] += h * wv[1];
      z[c4 * 4 + 2] += h * wv[2];
      z[c4 * 4 + 3] += h * wv[3];
    }
  }
  float mz = z[0];
#pragma unroll
  for (int c = 1; c < 40; ++c) mz = fmaxf(mz, z[c]);
  float se = 0.f;
#pragma unroll
  for (int c = 0; c < 40; ++c) se += expf(z[c] - mz);
  const float ls = logf(se);
#pragma unroll
  for (int c = 0; c < 40; ++c) zb[tid * 41 + c] = z[c] - mz - ls;
  __syncthreads();
  long rows = NR - n0; if (rows > 256) rows = 256;
  const long cnt = rows * 40;
  for (long i = tid; i < cnt; i += 256)
    out[n0 * 40 + i] = zb[(i / 40) * 41 + (i % 40)];
}

extern "C" void kernel_launch(void* const* d_in, const int* in_sizes, int n_in,
                              void* d_out, int out_size, void* d_ws, size_t ws_size,
                              hipStream_t stream) {
  const float* x      = (const float*)d_in[0];
  const float* e0     = (const float*)d_in[1];
  const float* e1     = (const float*)d_in[2];
  const float* u0     = (const float*)d_in[3];
  const float* u1     = (const float*)d_in[4];
  const float* fe_w1  = (const float*)d_in[5];
  const float* fe_b1  = (const float*)d_in[6];
  const float* fe_w2  = (const float*)d_in[7];
  const float* fe_b2  = (const float*)d_in[8];
  const float* eig_w  = (const float*)d_in[9];
  const float* eig_bi = (const float*)d_in[10];
  const float* lw     = (const float*)d_in[11];
  const float* ln_g   = (const float*)d_in[12];
  const float* ln_b   = (const float*)d_in[13];
  const float* fW     = (const float*)d_in[14];
  const float* att0   = (const float*)d_in[15];
  const float* att1   = (const float*)d_in[16];
  const float* att2   = (const float*)d_in[17];
  const float* attv   = (const float*)d_in[18];
  const float* lin3w  = (const float*)d_in[19];
  const float* lin3b  = (const float*)d_in[20];
  float* out = (float*)d_out;

  const size_t SZ_H = (size_t)NR * 128 * 2;        // 25,600,000
  const size_t SZ_P = (size_t)KC * 65536 * 2;      // 12,058,624 (bf16 partials)
  const size_t SZ_U = (size_t)NR * 512 * 2;        // 102,400,000

  char* p = (char*)d_ws;
  unsigned short* R0T = (unsigned short*)p; p += SZ_H;
  unsigned short* R1T = (unsigned short*)p; p += SZ_H;
  unsigned short* R2T = (unsigned short*)p; p += SZ_H;
  unsigned short* P   = (unsigned short*)p; p += SZ_P;
  unsigned short* W1T = (unsigned short*)p; p += 131072;
  unsigned short* W2T = (unsigned short*)p; p += 32768;
  unsigned short* sT  = (unsigned short*)p; p += 131072;
  float* eig          = (float*)p;          p += 4096;
  float* coef         = (float*)p;          p += 2048;
  const size_t base = (size_t)(p - (char*)d_ws);
  const bool full = ws_size >= base + 2 * SZ_U;
  unsigned short* UbT = nullptr;
  unsigned short* Ubf = nullptr;
  if (full) {
    UbT = (unsigned short*)p; p += SZ_U;
    Ubf = (unsigned short*)p; p += SZ_U;
  }

  k_prep<<<325, 256, 0, stream>>>(e0, e1, fe_w1, fe_w2, eig_w, eig_bi, lw, fW,
                                  W1T, W2T, eig, coef);
  const int GB64  = (int)((NR + 63) / 64);     // 1563
  const int GB128 = (int)((NR + 127) / 128);   // 782

  k_gemm1<<<GB128, 256, 0, stream>>>(x, W1T, fe_b1, R1T);   // t -> R1T
  k_gemm2<<<GB128, 256, 0, stream>>>(W2T, R1T, fe_b2, R0T);

  for (int b = 0; b < 2; ++b) {
    const float* u = b ? u1 : u0;
    if (full) k_cvtT<<<GB64 * 8, 256, 0, stream>>>(u, Ubf, UbT);
    // h carries across branches: branch 1 starts from branch 0's final h (R1T).
    const unsigned short* hin = (b == 0) ? R0T : R1T;
    unsigned short* hb = b ? R2T : R1T;   // L0 out; L1 runs in-place on hb
    for (int L = 0; L < 2; ++L) {
      unsigned short* hout = hb;
      if (full) k_utx<<<4 * KC, 256, 0, stream>>>(hin, UbT, P);
      else      k_utx0<<<8 * KC, 256, 0, stream>>>(hin, u, P);
      k_reduce<<<64, 256, 0, stream>>>(P, eig + b * 512, sT);
      if (full)
        k_rgemm<<<GB64, 256, 0, stream>>>(sT, Ubf, hin, hout,
            coef + L * 256, coef + L * 256 + 128, ln_g + L * 128, ln_b + L * 128);
      else
        k_rgemm64<<<GB64, 256, 0, stream>>>(sT, u, hin, hout,
            coef + L * 256, coef + L * 256 + 128, ln_g + L * 128, ln_b + L * 128);
      hin = hout;
    }
  }
  k_final<<<(int)((NR + 255) / 256), 256, 0, stream>>>(R0T, R1T, R2T,
      att0, att1, att2, attv, lin3w, lin3b, out);
}